// Round 14
// baseline (399.986 us; speedup 1.0000x reference)
//
#include <hip/hip_runtime.h>
#include <cstdint>
#include <cmath>

typedef unsigned short ushort_t;
typedef __bf16 bf16x8 __attribute__((ext_vector_type(8)));
typedef float f32x4 __attribute__((ext_vector_type(4)));
typedef ushort_t us4 __attribute__((ext_vector_type(4)));
typedef ushort_t us8 __attribute__((ext_vector_type(8)));

#define MFMA16(a, b, c) __builtin_amdgcn_mfma_f32_16x16x32_bf16(a, b, c, 0, 0, 0)
#define LOG2E 1.4426950408889634f

__device__ __forceinline__ ushort_t f2bf(float f) {
    union { __bf16 h; ushort_t u; } cv;
    cv.h = (__bf16)f;   // RNE
    return cv.u;
}

__device__ __forceinline__ void glds16(const ushort_t* g, ushort_t* s) {
    __builtin_amdgcn_global_load_lds(
        (const __attribute__((address_space(1))) void*)(g),
        (__attribute__((address_space(3))) void*)(s), 16, 0, 0);
}

// ---------------- fused cast f32 -> bf16 (Wq pre-scaled by log2e) + bucket LUT ----------------
// 2049 blocks, 4 coalesced float4 per thread (stride-256).
//   id < 1024        : X   — 1024 float4 per block; X = 1,048,576 float4 total  -> 1024 blocks
//   1024 <= id < 2048: W   — r=(id-1024)>>8 selects Wq/Wk/Wv/Wo (256 blocks each, 262,144 f4/W)
//   id == 2048       : bucket LUT
__global__ void cast_all_k(const float* __restrict__ x, const float* __restrict__ wq,
                           const float* __restrict__ wk, const float* __restrict__ wv,
                           const float* __restrict__ wo, ushort_t* __restrict__ xb,
                           ushort_t* __restrict__ wb, unsigned char* __restrict__ lut) {
    int id = blockIdx.x, t = threadIdx.x;
    if (id == 2048) {
        // T5 bucket LUT: delta = j - i in [-2047, 2047]
        for (int idx = t; idx < 4095; idx += 256) {
            int rel = idx - 2047;
            int bb = (rel > 0) ? 16 : 0;
            int rp = (rel < 0) ? -rel : rel;
            int add;
            if (rp < 8) {
                add = rp;
            } else {
                // match np: correctly-rounded f32 log, then f64 divide, trunc toward zero
                float lg = (float)::log((double)rp * 0.125);
                double tt = ((double)lg) / 2.772588722239781 * 8.0;
                int large = 8 + (int)tt;
                add = (large < 15) ? large : 15;
            }
            lut[idx] = (unsigned char)(bb + add);
        }
        return;
    }
    const float* src;
    ushort_t* dst;
    int base;
    float scale = 1.0f;
    if (id < 1024) {
        src = x; dst = xb; base = id * 1024;
    } else {
        int r = (id - 1024) >> 8;
        base = ((id - 1024) & 255) * 1024;
        src = (r == 0) ? wq : (r == 1) ? wk : (r == 2) ? wv : wo;
        dst = wb + (size_t)r * 1048576;
        if (r == 0) scale = LOG2E;
    }
#pragma unroll
    for (int i = 0; i < 4; ++i) {
        int idx = base + i * 256 + t;
        float4 v = ((const float4*)src)[idx];
        us4 o;
        o.x = f2bf(v.x * scale); o.y = f2bf(v.y * scale);
        o.z = f2bf(v.z * scale); o.w = f2bf(v.w * scale);
        ((us4*)dst)[idx] = o;
    }
}

// ---------------- output projection GEMM: 64x64 tile, 1024 blocks (4/CU perfect fit) --------
// C[M=4096, N=1024] f32 = A[4096,1024] * B[1024,1024]^T, K=1024, BK=64.
// R14: 64x64 tiles -> 1024 blocks; __launch_bounds__(256,4) (VGPR cap 128, liveness ~80) =
// 4 blocks/CU x 256 CU = exact co-resident fit, 16 waves/CU (2x R13's TLP), zero tail.
// Same per-element K/MFMA order as before -> bit-identical f32 output.
// XCD panel-grouping: d -> g=((d>>6)<<3)|(d&7) in [0,128), j=(d>>3)&7;
// mtile = g>>1, ntile = (g&1)*8+j. The 8 members of a group (same d mod 8 -> same XCD)
// share one 64-row A(Ctx)-panel.
__global__ __launch_bounds__(256, 4) void gemm_out_k(const ushort_t* __restrict__ A,
                                                     const ushort_t* __restrict__ B0,
                                                     float* __restrict__ C0) {
    __shared__ ushort_t As[64 * 64];
    __shared__ ushort_t Bs[64 * 64];
    const int tid = threadIdx.x;
    const int l = tid & 63, w = tid >> 6;
    const int quad = l >> 4, lc = l & 15;
    const int d = blockIdx.x;
    const int g = ((d >> 6) << 3) | (d & 7);   // 0..127
    const int j = (d >> 3) & 7;                // 0..7
    const int m0 = (g >> 1) * 64;
    const int n0 = ((g & 1) * 8 + j) * 64;

    f32x4 acc[4] = {};
    const int rA = l >> 3;
    const int cA = ((l & 7) ^ rA) * 8;   // swizzled global chunk

    for (int k0 = 0; k0 < 1024; k0 += 64) {
#pragma unroll
        for (int t = 0; t < 2; ++t) {
            int row = w * 16 + t * 8;
            glds16(A + (size_t)(m0 + row + rA) * 1024 + k0 + cA, &As[row * 64]);
            glds16(B0 + (size_t)(n0 + row + rA) * 1024 + k0 + cA, &Bs[row * 64]);
        }
        __syncthreads();
#pragma unroll
        for (int ko = 0; ko < 2; ++ko) {
            const int ch = (((ko * 4 + quad) ^ (lc & 7))) * 8;
            bf16x8 af[4];
#pragma unroll
            for (int mt = 0; mt < 4; ++mt)
                af[mt] = *(const bf16x8*)&As[(mt * 16 + lc) * 64 + ch];
            bf16x8 bfr = *(const bf16x8*)&Bs[(w * 16 + lc) * 64 + ch];
#pragma unroll
            for (int mt = 0; mt < 4; ++mt)
                acc[mt] = MFMA16(af[mt], bfr, acc[mt]);
        }
        __syncthreads();
    }
#pragma unroll
    for (int mt = 0; mt < 4; ++mt) {
        int col = n0 + w * 16 + lc;
#pragma unroll
        for (int r = 0; r < 4; ++r) {
            int row = m0 + mt * 16 + quad * 4 + r;
            C0[(size_t)row * 1024 + col] = acc[mt][r];
        }
    }
}

// ---------------- fused Q + K + V^T GEMM: one 768-block dispatch, K=1024 hardcoded ----------
// XCD panel-grouping swizzle (T1): dispatch d -> (group g, member j), g = ((d>>6)<<3)|(d&7),
// j = (d>>3)&7. All 8 members of a group have d == g (mod 8) -> same XCD.
//   g <  64 : QK  (z = g>>5, m = g&31): tile m0 = m*128 (A-panel, shared by the 8 members),
//             n0 = j*128. A-panel fetched 1x/XCD instead of 8x.
//   g >= 64 : VT  (n = g-64): n0 = n*128 (Xb B-panel, shared by members), m0 = j*128.
// __launch_bounds__(256, 3): 3 blocks/CU -> all 768 blocks co-resident (perfect 3x256 fit).
__global__ __launch_bounds__(256, 3) void gemm_qkvt_k(const ushort_t* __restrict__ Xb,
                                                      const ushort_t* __restrict__ Wb,
                                                      ushort_t* __restrict__ QKg,
                                                      ushort_t* __restrict__ VTg) {
    __shared__ ushort_t As[128 * 64];
    __shared__ ushort_t Bs[128 * 64];
    const int tid = threadIdx.x;
    const int l = tid & 63, w = tid >> 6;
    const int quad = l >> 4, lc = l & 15;
    const int wm = w >> 1, wn = w & 1;
    const int d = blockIdx.x;
    const int g = ((d >> 6) << 3) | (d & 7);   // panel group 0..95
    const int j = (d >> 3) & 7;                // member 0..7

    const ushort_t* A;
    const ushort_t* B;
    int m0, n0, z = 0;
    bool vt;
    if (g < 64) {
        vt = false; z = g >> 5;
        m0 = (g & 31) * 128; n0 = j * 128;
        A = Xb; B = Wb + z * 1048576;
    } else {
        vt = true;
        m0 = j * 128; n0 = (g - 64) * 128;
        A = Wb + 2097152; B = Xb;
    }

    f32x4 acc[4][4] = {};
    const int rA = l >> 3;
    const int cA = ((l & 7) ^ rA) * 8;

    for (int k0 = 0; k0 < 1024; k0 += 64) {
#pragma unroll
        for (int t = 0; t < 4; ++t) {
            int row = w * 32 + t * 8;
            glds16(A + (size_t)(m0 + row + rA) * 1024 + k0 + cA, &As[row * 64]);
            glds16(B + (size_t)(n0 + row + rA) * 1024 + k0 + cA, &Bs[row * 64]);
        }
        __syncthreads();
#pragma unroll
        for (int ko = 0; ko < 2; ++ko) {
            const int ch = (((ko * 4 + quad) ^ (lc & 7))) * 8;
            bf16x8 af[4], bfr[4];
#pragma unroll
            for (int mt = 0; mt < 4; ++mt)
                af[mt] = *(const bf16x8*)&As[(wm * 64 + mt * 16 + lc) * 64 + ch];
#pragma unroll
            for (int nt = 0; nt < 4; ++nt)
                bfr[nt] = *(const bf16x8*)&Bs[(wn * 64 + nt * 16 + lc) * 64 + ch];
#pragma unroll
            for (int mt = 0; mt < 4; ++mt)
#pragma unroll
                for (int nt = 0; nt < 4; ++nt)
                    acc[mt][nt] = MFMA16(af[mt], bfr[nt], acc[mt][nt]);
        }
        __syncthreads();
    }
#pragma unroll
    for (int mt = 0; mt < 4; ++mt) {
#pragma unroll
        for (int nt = 0; nt < 4; ++nt) {
            int col = n0 + wn * 64 + nt * 16 + lc;
#pragma unroll
            for (int r = 0; r < 4; ++r) {
                int row = m0 + wm * 64 + mt * 16 + quad * 4 + r;
                if (!vt) {
                    QKg[(size_t)z * 4194304 + (size_t)row * 1024 + col] = f2bf(acc[mt][nt][r]);
                } else {
                    VTg[(size_t)(col >> 11) * 2097152 + (size_t)row * 2048 + (col & 2047)] =
                        f2bf(acc[mt][nt][r]);
                }
            }
        }
    }
}

// ---------------- flash attention, S^T = K*Q^T, 1 barrier/kt, K dbuf, V direct ----------------
// R5-exact (best verified). Four attn perturbations (R1/R6/R7/R8) all regressed:
// this kernel sits on a register-allocation cliff — DO NOT TOUCH.
__global__ __launch_bounds__(256, 2) void attn_k(const ushort_t* __restrict__ Qg,
                                                 const ushort_t* __restrict__ Kg,
                                                 const ushort_t* __restrict__ VTg,
                                                 ushort_t* __restrict__ Ctx,
                                                 const unsigned char* __restrict__ lut,
                                                 const float* __restrict__ table,
                                                 float* __restrict__ bias_out) {
    __shared__ ushort_t Kbuf[2][128 * 64];              // K tiles [j][d] swizzled, double-buffered
    __shared__ ushort_t Pws[4 * 32 * 40];               // per-wave packed P [q][j-chunk]
    __shared__ alignas(16) float diag4[2][4 * 256];     // 4 shifted copies of raw bias diagonal, dbuf

    const int tid = threadIdx.x, l = tid & 63, w = tid >> 6;
    const int quad = l >> 4, lc = l & 15;
    const int id = blockIdx.x;
    const int bh = id & 31, b = bh >> 4, h = bh & 15;
    const int q0 = (id >> 5) * 128;
    const size_t tokbase = (size_t)b * 2048;

    const int rK = l >> 3;
    const int cK = ((l & 7) ^ rK) * 8;

    // ---- prologue: Q -> Kbuf[1], K(kt0) -> Kbuf[0], diag4[0] ----
#pragma unroll
    for (int t = 0; t < 4; ++t) {
        int row0 = w * 32 + t * 8;
        glds16(Qg + (tokbase + q0 + row0 + rK) * 1024 + h * 64 + cK, &Kbuf[1][row0 * 64]);
        glds16(Kg + (tokbase + row0 + rK) * 1024 + h * 64 + cK, &Kbuf[0][row0 * 64]);
    }
    if (tid < 255) {
        float v0 = table[(int)lut[tid + 1920 - q0] * 16 + h];
        float* dg = diag4[0];
        dg[tid] = v0;
        if (tid >= 1) dg[255 + tid] = v0;   // copy1[tid-1]
        if (tid >= 2) dg[510 + tid] = v0;   // copy2[tid-2]
        if (tid >= 3) dg[765 + tid] = v0;   // copy3[tid-3]
    }
    __syncthreads();

    // Q fragments (B-operand): lane holds Q[w*32+nt*16+lc][ko*32+quad*8+i]
    bf16x8 qf[2][2];
#pragma unroll
    for (int nt = 0; nt < 2; ++nt)
#pragma unroll
        for (int ko = 0; ko < 2; ++ko) {
            int row = w * 32 + nt * 16 + lc;
            int ch = ((ko * 4 + quad) ^ (lc & 7)) * 8;
            qf[nt][ko] = *(const bf16x8*)&Kbuf[1][row * 64 + ch];
        }
    __syncthreads();   // Kbuf[1] free for kt=0's prefetch of K(kt=1)

    float mstate[2] = {-1e30f, -1e30f};
    float lstate[2] = {0.f, 0.f};
    f32x4 acco[4][2] = {};
    ushort_t* Pw = &Pws[w * 1280];         // 32 q-rows x 40 u16
    const int cb0 = quad * 4 - (w * 32 + lc) + 127;
    const int cxor = lc & 3;               // P chunk swizzle
    const ushort_t* VTbase = VTg + (size_t)(b * 1024 + h * 64) * 2048;

    const int bjf = (tid & 15) * 4 + b * 64;   // bias patch j offset within 128-tile
    const int big = tid >> 4;
    const int d00 = bjf - big + 127;           // store-path diag index at rr=0
    const int sb = cb0 & 3, bb = cb0 & ~3;     // bias-add copy select / aligned base
    const int ss = d00 & 3, db = d00 & ~3;     // store-path copy select / aligned base

    for (int kt = 0; kt < 16; ++kt) {
        const int j0 = kt * 128;
        const int cur = kt & 1, nxt = cur ^ 1;
        const ushort_t* Kc = Kbuf[cur];
        const float* dc = diag4[cur];

        // ---- prefetch next K tile + next bias diagonal (drains behind this kt's compute) ----
        if (kt < 15) {
            const int jn = j0 + 128;
#pragma unroll
            for (int t = 0; t < 4; ++t) {
                int row0 = w * 32 + t * 8;
                glds16(Kg + (tokbase + jn + row0 + rK) * 1024 + h * 64 + cK, &Kbuf[nxt][row0 * 64]);
            }
            if (tid < 255) {
                float vv = table[(int)lut[jn - q0 + tid + 1920] * 16 + h];
                float* dg = diag4[nxt];
                dg[tid] = vv;
                if (tid >= 1) dg[255 + tid] = vv;
                if (tid >= 2) dg[510 + tid] = vv;
                if (tid >= 3) dg[765 + tid] = vv;
            }
        }

        // ---- V fragments direct from global (A-operand rows d, k-index j) ----
        bf16x8 vf[4][4];
#pragma unroll
        for (int kk = 0; kk < 4; ++kk)
#pragma unroll
            for (int dt = 0; dt < 4; ++dt)
                vf[kk][dt] = *(const bf16x8*)(VTbase + (size_t)(dt * 16 + lc) * 2048 +
                                              j0 + kk * 32 + quad * 8);

        // ---- fused position_bias patch store (aligned b128 diag reads; issued early) ----
        {
            float* outp = bias_out + ((size_t)h * 2048 + q0) * 2048 + j0;
            const float* dsp = dc + ss * 256;
#pragma unroll
            for (int rr = 0; rr < 8; ++rr) {
                int il = big + 16 * rr;
                f32x4 v = *(const f32x4*)&dsp[db - 16 * rr];
                __builtin_nontemporal_store(v, (f32x4*)(outp + (size_t)il * 2048 + bjf));
            }
        }

        // ---- S^T = K Q^T : D[j][q], A = K rows, B = Q rows (Q pre-scaled by log2e) ----
        f32x4 accs[8][2] = {};
#pragma unroll
        for (int ko = 0; ko < 2; ++ko) {
            const int ch = ((ko * 4 + quad) ^ (lc & 7)) * 8;
#pragma unroll
            for (int mt = 0; mt < 8; ++mt) {
                bf16x8 kf = *(const bf16x8*)&Kc[(mt * 16 + lc) * 64 + ch];
                accs[mt][0] = MFMA16(kf, qf[0][ko], accs[mt][0]);
                accs[mt][1] = MFMA16(kf, qf[1][ko], accs[mt][1]);
            }
        }

        // ---- + bias via fma(raw, log2e), aligned b128 diag reads, rolling reuse ----
        {
            const float* dcp = dc + sb * 256;
            f32x4 dprev4 = *(const f32x4*)&dcp[bb - 16];
#pragma unroll
            for (int mt = 0; mt < 8; ++mt) {
                f32x4 dcur4 = *(const f32x4*)&dcp[bb + mt * 16];
#pragma unroll
                for (int r = 0; r < 4; ++r) {
                    accs[mt][0][r] = fmaf(dcur4[r], LOG2E, accs[mt][0][r]);
                    accs[mt][1][r] = fmaf(dprev4[r], LOG2E, accs[mt][1][r]);
                }
                dprev4 = dcur4;
            }
        }

        // ---- online softmax in exp2 domain: q-row = nt*16+lc over 4 quad-lanes ----
#pragma unroll
        for (int nt = 0; nt < 2; ++nt) {
            float mx = accs[0][nt][0];
#pragma unroll
            for (int mt = 0; mt < 8; ++mt)
#pragma unroll
                for (int r = 0; r < 4; ++r) mx = fmaxf(mx, accs[mt][nt][r]);
            mx = fmaxf(mx, __shfl_xor(mx, 16, 64));
            mx = fmaxf(mx, __shfl_xor(mx, 32, 64));
            float mo = mstate[nt], mn = fmaxf(mo, mx);
            float alpha = __builtin_amdgcn_exp2f(mo - mn);
            mstate[nt] = mn;
            float rs = 0.f;
#pragma unroll
            for (int mt = 0; mt < 8; ++mt)
#pragma unroll
                for (int r = 0; r < 4; ++r) {
                    float p = __builtin_amdgcn_exp2f(accs[mt][nt][r] - mn);
                    accs[mt][nt][r] = p;
                    rs += p;
                }
            rs += __shfl_xor(rs, 16, 64);
            rs += __shfl_xor(rs, 32, 64);
            lstate[nt] = lstate[nt] * alpha + rs;
#pragma unroll
            for (int dt = 0; dt < 4; ++dt) acco[dt][nt] *= alpha;
        }

        // ---- O^T += V^T P^T; P packed as [q][j-chunk] (b64 writes, b128 reads) ----
#pragma unroll
        for (int kk = 0; kk < 4; ++kk) {
#pragma unroll
            for (int half = 0; half < 2; ++half) {
                int mt = kk * 2 + half;
                int c = half * 2 + (quad >> 1);
                int coff = ((c ^ cxor) * 8 + (quad & 1) * 4);
#pragma unroll
                for (int nt = 0; nt < 2; ++nt) {
                    us4 o;
#pragma unroll
                    for (int r = 0; r < 4; ++r) o[r] = f2bf(accs[mt][nt][r]);
                    *(us4*)&Pw[(nt * 16 + lc) * 40 + coff] = o;
                }
            }
            bf16x8 pf[2];
#pragma unroll
            for (int nt = 0; nt < 2; ++nt)
                pf[nt] = *(const bf16x8*)&Pw[(nt * 16 + lc) * 40 + (quad ^ cxor) * 8];
#pragma unroll
            for (int dt = 0; dt < 4; ++dt)
#pragma unroll
                for (int nt = 0; nt < 2; ++nt)
                    acco[dt][nt] = MFMA16(vf[kk][dt], pf[nt], acco[dt][nt]);
        }
        if (kt < 15) {
            // counted-vmcnt barrier: let the 8 NT bias stores float across; everything older
            // (glds16 K-prefetch, V loads) is in-order-retired at <=8 outstanding.
            asm volatile("s_waitcnt vmcnt(8) lgkmcnt(0)" ::: "memory");
            __builtin_amdgcn_s_barrier();
            __builtin_amdgcn_sched_barrier(0);
        }
    }

    // ---- epilogue: O^T lane holds (d = dt*16+quad*4+r, q = w*32+nt*16+lc) ----
#pragma unroll
    for (int nt = 0; nt < 2; ++nt) {
        float inv = 1.0f / lstate[nt];
        size_t row = tokbase + q0 + w * 32 + nt * 16 + lc;
#pragma unroll
        for (int dt = 0; dt < 4; ++dt) {
            us4 o;
#pragma unroll
            for (int r = 0; r < 4; ++r) o[r] = f2bf(acco[dt][nt][r] * inv);
            *(us4*)&Ctx[row * 1024 + h * 64 + dt * 16 + quad * 4] = o;
        }
    }
}

extern "C" void kernel_launch(void* const* d_in, const int* in_sizes, int n_in,
                              void* d_out, int out_size, void* d_ws, size_t ws_size,
                              hipStream_t stream) {
    const float* hidden = (const float*)d_in[0];
    const float* Wq = (const float*)d_in[1];
    const float* Wk = (const float*)d_in[2];
    const float* Wv = (const float*)d_in[3];
    const float* Wo = (const float*)d_in[4];
    const float* table = (const float*)d_in[5];

    char* ws = (char*)d_ws;
    ushort_t* Xb  = (ushort_t*)(ws);                    // [4096][1024] bf16
    ushort_t* Wb  = (ushort_t*)(ws + 8388608);          // Wq(*log2e),Wk,Wv,Wo each [1024][1024]
    ushort_t* Qg  = (ushort_t*)(ws + 16777216);         // [4096][1024]
    ushort_t* Kgp = (ushort_t*)(ws + 25165824);         // [4096][1024]
    ushort_t* VTg = (ushort_t*)(ws + 33554432);         // [(b*1024+f)][2048]
    ushort_t* Ctx = (ushort_t*)(ws + 41943040);         // [4096][1024]
    unsigned char* lutp = (unsigned char*)(ws + 50331648);

    float* out0 = (float*)d_out;
    float* out1 = out0 + 4194304;

    cast_all_k<<<2049, 256, 0, stream>>>(hidden, Wq, Wk, Wv, Wo, Xb, Wb, lutp);

    // Q, K projections + V^T in one fused dispatch (768 blocks = 3/CU perfect fit)
    gemm_qkvt_k<<<768, 256, 0, stream>>>(Xb, Wb, Qg, VTg);

    attn_k<<<dim3(512), 256, 0, stream>>>(Qg, Kgp, VTg, Ctx, lutp, table, out1);

    // output projection: 64x64 tiles -> 1024 blocks (4/CU perfect fit), XCD panel-grouped
    gemm_out_k<<<1024, 256, 0, stream>>>(Ctx, Wb + 3145728, out0);
}

// Round 15
// 389.737 us; speedup vs baseline: 1.0263x; 1.0263x over previous
//
#include <hip/hip_runtime.h>
#include <cstdint>
#include <cmath>

typedef unsigned short ushort_t;
typedef __bf16 bf16x8 __attribute__((ext_vector_type(8)));
typedef float f32x4 __attribute__((ext_vector_type(4)));
typedef ushort_t us4 __attribute__((ext_vector_type(4)));
typedef ushort_t us8 __attribute__((ext_vector_type(8)));

#define MFMA16(a, b, c) __builtin_amdgcn_mfma_f32_16x16x32_bf16(a, b, c, 0, 0, 0)
#define LOG2E 1.4426950408889634f

__device__ __forceinline__ ushort_t f2bf(float f) {
    union { __bf16 h; ushort_t u; } cv;
    cv.h = (__bf16)f;   // RNE
    return cv.u;
}

__device__ __forceinline__ void glds16(const ushort_t* g, ushort_t* s) {
    __builtin_amdgcn_global_load_lds(
        (const __attribute__((address_space(1))) void*)(g),
        (__attribute__((address_space(3))) void*)(s), 16, 0, 0);
}

// ---------------- fused cast f32 -> bf16 (Wq pre-scaled by log2e) + bucket LUT ----------------
// 2049 blocks, 4 coalesced float4 per thread (stride-256).
//   id < 1024        : X   — 1024 float4 per block; X = 1,048,576 float4 total  -> 1024 blocks
//   1024 <= id < 2048: W   — r=(id-1024)>>8 selects Wq/Wk/Wv/Wo (256 blocks each, 262,144 f4/W)
//   id == 2048       : bucket LUT
__global__ void cast_all_k(const float* __restrict__ x, const float* __restrict__ wq,
                           const float* __restrict__ wk, const float* __restrict__ wv,
                           const float* __restrict__ wo, ushort_t* __restrict__ xb,
                           ushort_t* __restrict__ wb, unsigned char* __restrict__ lut) {
    int id = blockIdx.x, t = threadIdx.x;
    if (id == 2048) {
        // T5 bucket LUT: delta = j - i in [-2047, 2047]
        for (int idx = t; idx < 4095; idx += 256) {
            int rel = idx - 2047;
            int bb = (rel > 0) ? 16 : 0;
            int rp = (rel < 0) ? -rel : rel;
            int add;
            if (rp < 8) {
                add = rp;
            } else {
                // match np: correctly-rounded f32 log, then f64 divide, trunc toward zero
                float lg = (float)::log((double)rp * 0.125);
                double tt = ((double)lg) / 2.772588722239781 * 8.0;
                int large = 8 + (int)tt;
                add = (large < 15) ? large : 15;
            }
            lut[idx] = (unsigned char)(bb + add);
        }
        return;
    }
    const float* src;
    ushort_t* dst;
    int base;
    float scale = 1.0f;
    if (id < 1024) {
        src = x; dst = xb; base = id * 1024;
    } else {
        int r = (id - 1024) >> 8;
        base = ((id - 1024) & 255) * 1024;
        src = (r == 0) ? wq : (r == 1) ? wk : (r == 2) ? wv : wo;
        dst = wb + (size_t)r * 1048576;
        if (r == 0) scale = LOG2E;
    }
#pragma unroll
    for (int i = 0; i < 4; ++i) {
        int idx = base + i * 256 + t;
        float4 v = ((const float4*)src)[idx];
        us4 o;
        o.x = f2bf(v.x * scale); o.y = f2bf(v.y * scale);
        o.z = f2bf(v.z * scale); o.w = f2bf(v.w * scale);
        ((us4*)dst)[idx] = o;
    }
}

// ---------------- output projection GEMM: 64x128 tile, 512 blocks (2/CU) ----------------
// C[M=4096, N=1024] f32 = A[4096,1024] * B[1024,1024]^T, K=1024, BK=64.
// XCD panel-grouping swizzle (T1): the 8 n-tiles sharing one 64-row A(Ctx)-panel get dispatch
// ids == same value mod 8 -> same XCD L2 -> A-panel fetched 1x instead of 8x from L3.
// d = (m>>3)*64 + n*8 + (m&7)  (bijective on [0,512));  kernel inverts it.
// R15: reverted to this R13-verified version (R14's 64x64/4-per-CU retile cost +2.6 us:
// smaller tile's MFMA:staging ratio loss > TLP gain; gemm_out at 512x2/CU has no tail).
__global__ __launch_bounds__(256) void gemm_out_k(const ushort_t* __restrict__ A,
                                                  const ushort_t* __restrict__ B0,
                                                  float* __restrict__ C0) {
    __shared__ ushort_t As[64 * 64];
    __shared__ ushort_t Bs[128 * 64];
    const int tid = threadIdx.x;
    const int l = tid & 63, w = tid >> 6;
    const int quad = l >> 4, lc = l & 15;
    const int d = blockIdx.x;
    const int mtile = ((d >> 6) << 3) | (d & 7);   // 0..63
    const int ntile = (d >> 3) & 7;                // 0..7
    const int m0 = mtile * 64, n0 = ntile * 128;

    f32x4 acc[4][2] = {};
    const int rA = l >> 3;
    const int cA = ((l & 7) ^ rA) * 8;   // swizzled global chunk

    for (int k0 = 0; k0 < 1024; k0 += 64) {
#pragma unroll
        for (int t = 0; t < 2; ++t) {
            int row = w * 16 + t * 8;
            glds16(A + (size_t)(m0 + row + rA) * 1024 + k0 + cA, &As[row * 64]);
        }
#pragma unroll
        for (int t = 0; t < 4; ++t) {
            int row = w * 32 + t * 8;
            glds16(B0 + (size_t)(n0 + row + rA) * 1024 + k0 + cA, &Bs[row * 64]);
        }
        __syncthreads();
#pragma unroll
        for (int ko = 0; ko < 2; ++ko) {
            const int ch = (((ko * 4 + quad) ^ (lc & 7))) * 8;
            bf16x8 af[4], bfr[2];
#pragma unroll
            for (int mt = 0; mt < 4; ++mt)
                af[mt] = *(const bf16x8*)&As[(mt * 16 + lc) * 64 + ch];
#pragma unroll
            for (int nt = 0; nt < 2; ++nt)
                bfr[nt] = *(const bf16x8*)&Bs[(w * 32 + nt * 16 + lc) * 64 + ch];
#pragma unroll
            for (int mt = 0; mt < 4; ++mt)
#pragma unroll
                for (int nt = 0; nt < 2; ++nt)
                    acc[mt][nt] = MFMA16(af[mt], bfr[nt], acc[mt][nt]);
        }
        __syncthreads();
    }
#pragma unroll
    for (int mt = 0; mt < 4; ++mt) {
#pragma unroll
        for (int nt = 0; nt < 2; ++nt) {
            int col = n0 + w * 32 + nt * 16 + lc;
#pragma unroll
            for (int r = 0; r < 4; ++r) {
                int row = m0 + mt * 16 + quad * 4 + r;
                C0[(size_t)row * 1024 + col] = acc[mt][nt][r];
            }
        }
    }
}

// ---------------- fused Q + K + V^T GEMM: one 768-block dispatch, K=1024 hardcoded ----------
// XCD panel-grouping swizzle (T1): dispatch d -> (group g, member j), g = ((d>>6)<<3)|(d&7),
// j = (d>>3)&7. All 8 members of a group have d == g (mod 8) -> same XCD.
//   g <  64 : QK  (z = g>>5, m = g&31): tile m0 = m*128 (A-panel, shared by the 8 members),
//             n0 = j*128. A-panel fetched 1x/XCD instead of 8x.
//   g >= 64 : VT  (n = g-64): n0 = n*128 (Xb B-panel, shared by members), m0 = j*128.
// __launch_bounds__(256, 3): 3 blocks/CU -> all 768 blocks co-resident (perfect 3x256 fit).
__global__ __launch_bounds__(256, 3) void gemm_qkvt_k(const ushort_t* __restrict__ Xb,
                                                      const ushort_t* __restrict__ Wb,
                                                      ushort_t* __restrict__ QKg,
                                                      ushort_t* __restrict__ VTg) {
    __shared__ ushort_t As[128 * 64];
    __shared__ ushort_t Bs[128 * 64];
    const int tid = threadIdx.x;
    const int l = tid & 63, w = tid >> 6;
    const int quad = l >> 4, lc = l & 15;
    const int wm = w >> 1, wn = w & 1;
    const int d = blockIdx.x;
    const int g = ((d >> 6) << 3) | (d & 7);   // panel group 0..95
    const int j = (d >> 3) & 7;                // member 0..7

    const ushort_t* A;
    const ushort_t* B;
    int m0, n0, z = 0;
    bool vt;
    if (g < 64) {
        vt = false; z = g >> 5;
        m0 = (g & 31) * 128; n0 = j * 128;
        A = Xb; B = Wb + z * 1048576;
    } else {
        vt = true;
        m0 = j * 128; n0 = (g - 64) * 128;
        A = Wb + 2097152; B = Xb;
    }

    f32x4 acc[4][4] = {};
    const int rA = l >> 3;
    const int cA = ((l & 7) ^ rA) * 8;

    for (int k0 = 0; k0 < 1024; k0 += 64) {
#pragma unroll
        for (int t = 0; t < 4; ++t) {
            int row = w * 32 + t * 8;
            glds16(A + (size_t)(m0 + row + rA) * 1024 + k0 + cA, &As[row * 64]);
            glds16(B + (size_t)(n0 + row + rA) * 1024 + k0 + cA, &Bs[row * 64]);
        }
        __syncthreads();
#pragma unroll
        for (int ko = 0; ko < 2; ++ko) {
            const int ch = (((ko * 4 + quad) ^ (lc & 7))) * 8;
            bf16x8 af[4], bfr[4];
#pragma unroll
            for (int mt = 0; mt < 4; ++mt)
                af[mt] = *(const bf16x8*)&As[(wm * 64 + mt * 16 + lc) * 64 + ch];
#pragma unroll
            for (int nt = 0; nt < 4; ++nt)
                bfr[nt] = *(const bf16x8*)&Bs[(wn * 64 + nt * 16 + lc) * 64 + ch];
#pragma unroll
            for (int mt = 0; mt < 4; ++mt)
#pragma unroll
                for (int nt = 0; nt < 4; ++nt)
                    acc[mt][nt] = MFMA16(af[mt], bfr[nt], acc[mt][nt]);
        }
        __syncthreads();
    }
#pragma unroll
    for (int mt = 0; mt < 4; ++mt) {
#pragma unroll
        for (int nt = 0; nt < 4; ++nt) {
            int col = n0 + wn * 64 + nt * 16 + lc;
#pragma unroll
            for (int r = 0; r < 4; ++r) {
                int row = m0 + wm * 64 + mt * 16 + quad * 4 + r;
                if (!vt) {
                    QKg[(size_t)z * 4194304 + (size_t)row * 1024 + col] = f2bf(acc[mt][nt][r]);
                } else {
                    VTg[(size_t)(col >> 11) * 2097152 + (size_t)row * 2048 + (col & 2047)] =
                        f2bf(acc[mt][nt][r]);
                }
            }
        }
    }
}

// ---------------- flash attention, S^T = K*Q^T, 1 barrier/kt, K dbuf, V direct ----------------
// R5-exact (best verified). Four attn perturbations (R1/R6/R7/R8) all regressed:
// this kernel sits on a register-allocation cliff — DO NOT TOUCH.
__global__ __launch_bounds__(256, 2) void attn_k(const ushort_t* __restrict__ Qg,
                                                 const ushort_t* __restrict__ Kg,
                                                 const ushort_t* __restrict__ VTg,
                                                 ushort_t* __restrict__ Ctx,
                                                 const unsigned char* __restrict__ lut,
                                                 const float* __restrict__ table,
                                                 float* __restrict__ bias_out) {
    __shared__ ushort_t Kbuf[2][128 * 64];              // K tiles [j][d] swizzled, double-buffered
    __shared__ ushort_t Pws[4 * 32 * 40];               // per-wave packed P [q][j-chunk]
    __shared__ alignas(16) float diag4[2][4 * 256];     // 4 shifted copies of raw bias diagonal, dbuf

    const int tid = threadIdx.x, l = tid & 63, w = tid >> 6;
    const int quad = l >> 4, lc = l & 15;
    const int id = blockIdx.x;
    const int bh = id & 31, b = bh >> 4, h = bh & 15;
    const int q0 = (id >> 5) * 128;
    const size_t tokbase = (size_t)b * 2048;

    const int rK = l >> 3;
    const int cK = ((l & 7) ^ rK) * 8;

    // ---- prologue: Q -> Kbuf[1], K(kt0) -> Kbuf[0], diag4[0] ----
#pragma unroll
    for (int t = 0; t < 4; ++t) {
        int row0 = w * 32 + t * 8;
        glds16(Qg + (tokbase + q0 + row0 + rK) * 1024 + h * 64 + cK, &Kbuf[1][row0 * 64]);
        glds16(Kg + (tokbase + row0 + rK) * 1024 + h * 64 + cK, &Kbuf[0][row0 * 64]);
    }
    if (tid < 255) {
        float v0 = table[(int)lut[tid + 1920 - q0] * 16 + h];
        float* dg = diag4[0];
        dg[tid] = v0;
        if (tid >= 1) dg[255 + tid] = v0;   // copy1[tid-1]
        if (tid >= 2) dg[510 + tid] = v0;   // copy2[tid-2]
        if (tid >= 3) dg[765 + tid] = v0;   // copy3[tid-3]
    }
    __syncthreads();

    // Q fragments (B-operand): lane holds Q[w*32+nt*16+lc][ko*32+quad*8+i]
    bf16x8 qf[2][2];
#pragma unroll
    for (int nt = 0; nt < 2; ++nt)
#pragma unroll
        for (int ko = 0; ko < 2; ++ko) {
            int row = w * 32 + nt * 16 + lc;
            int ch = ((ko * 4 + quad) ^ (lc & 7)) * 8;
            qf[nt][ko] = *(const bf16x8*)&Kbuf[1][row * 64 + ch];
        }
    __syncthreads();   // Kbuf[1] free for kt=0's prefetch of K(kt=1)

    float mstate[2] = {-1e30f, -1e30f};
    float lstate[2] = {0.f, 0.f};
    f32x4 acco[4][2] = {};
    ushort_t* Pw = &Pws[w * 1280];         // 32 q-rows x 40 u16
    const int cb0 = quad * 4 - (w * 32 + lc) + 127;
    const int cxor = lc & 3;               // P chunk swizzle
    const ushort_t* VTbase = VTg + (size_t)(b * 1024 + h * 64) * 2048;

    const int bjf = (tid & 15) * 4 + b * 64;   // bias patch j offset within 128-tile
    const int big = tid >> 4;
    const int d00 = bjf - big + 127;           // store-path diag index at rr=0
    const int sb = cb0 & 3, bb = cb0 & ~3;     // bias-add copy select / aligned base
    const int ss = d00 & 3, db = d00 & ~3;     // store-path copy select / aligned base

    for (int kt = 0; kt < 16; ++kt) {
        const int j0 = kt * 128;
        const int cur = kt & 1, nxt = cur ^ 1;
        const ushort_t* Kc = Kbuf[cur];
        const float* dc = diag4[cur];

        // ---- prefetch next K tile + next bias diagonal (drains behind this kt's compute) ----
        if (kt < 15) {
            const int jn = j0 + 128;
#pragma unroll
            for (int t = 0; t < 4; ++t) {
                int row0 = w * 32 + t * 8;
                glds16(Kg + (tokbase + jn + row0 + rK) * 1024 + h * 64 + cK, &Kbuf[nxt][row0 * 64]);
            }
            if (tid < 255) {
                float vv = table[(int)lut[jn - q0 + tid + 1920] * 16 + h];
                float* dg = diag4[nxt];
                dg[tid] = vv;
                if (tid >= 1) dg[255 + tid] = vv;
                if (tid >= 2) dg[510 + tid] = vv;
                if (tid >= 3) dg[765 + tid] = vv;
            }
        }

        // ---- V fragments direct from global (A-operand rows d, k-index j) ----
        bf16x8 vf[4][4];
#pragma unroll
        for (int kk = 0; kk < 4; ++kk)
#pragma unroll
            for (int dt = 0; dt < 4; ++dt)
                vf[kk][dt] = *(const bf16x8*)(VTbase + (size_t)(dt * 16 + lc) * 2048 +
                                              j0 + kk * 32 + quad * 8);

        // ---- fused position_bias patch store (aligned b128 diag reads; issued early) ----
        {
            float* outp = bias_out + ((size_t)h * 2048 + q0) * 2048 + j0;
            const float* dsp = dc + ss * 256;
#pragma unroll
            for (int rr = 0; rr < 8; ++rr) {
                int il = big + 16 * rr;
                f32x4 v = *(const f32x4*)&dsp[db - 16 * rr];
                __builtin_nontemporal_store(v, (f32x4*)(outp + (size_t)il * 2048 + bjf));
            }
        }

        // ---- S^T = K Q^T : D[j][q], A = K rows, B = Q rows (Q pre-scaled by log2e) ----
        f32x4 accs[8][2] = {};
#pragma unroll
        for (int ko = 0; ko < 2; ++ko) {
            const int ch = ((ko * 4 + quad) ^ (lc & 7)) * 8;
#pragma unroll
            for (int mt = 0; mt < 8; ++mt) {
                bf16x8 kf = *(const bf16x8*)&Kc[(mt * 16 + lc) * 64 + ch];
                accs[mt][0] = MFMA16(kf, qf[0][ko], accs[mt][0]);
                accs[mt][1] = MFMA16(kf, qf[1][ko], accs[mt][1]);
            }
        }

        // ---- + bias via fma(raw, log2e), aligned b128 diag reads, rolling reuse ----
        {
            const float* dcp = dc + sb * 256;
            f32x4 dprev4 = *(const f32x4*)&dcp[bb - 16];
#pragma unroll
            for (int mt = 0; mt < 8; ++mt) {
                f32x4 dcur4 = *(const f32x4*)&dcp[bb + mt * 16];
#pragma unroll
                for (int r = 0; r < 4; ++r) {
                    accs[mt][0][r] = fmaf(dcur4[r], LOG2E, accs[mt][0][r]);
                    accs[mt][1][r] = fmaf(dprev4[r], LOG2E, accs[mt][1][r]);
                }
                dprev4 = dcur4;
            }
        }

        // ---- online softmax in exp2 domain: q-row = nt*16+lc over 4 quad-lanes ----
#pragma unroll
        for (int nt = 0; nt < 2; ++nt) {
            float mx = accs[0][nt][0];
#pragma unroll
            for (int mt = 0; mt < 8; ++mt)
#pragma unroll
                for (int r = 0; r < 4; ++r) mx = fmaxf(mx, accs[mt][nt][r]);
            mx = fmaxf(mx, __shfl_xor(mx, 16, 64));
            mx = fmaxf(mx, __shfl_xor(mx, 32, 64));
            float mo = mstate[nt], mn = fmaxf(mo, mx);
            float alpha = __builtin_amdgcn_exp2f(mo - mn);
            mstate[nt] = mn;
            float rs = 0.f;
#pragma unroll
            for (int mt = 0; mt < 8; ++mt)
#pragma unroll
                for (int r = 0; r < 4; ++r) {
                    float p = __builtin_amdgcn_exp2f(accs[mt][nt][r] - mn);
                    accs[mt][nt][r] = p;
                    rs += p;
                }
            rs += __shfl_xor(rs, 16, 64);
            rs += __shfl_xor(rs, 32, 64);
            lstate[nt] = lstate[nt] * alpha + rs;
#pragma unroll
            for (int dt = 0; dt < 4; ++dt) acco[dt][nt] *= alpha;
        }

        // ---- O^T += V^T P^T; P packed as [q][j-chunk] (b64 writes, b128 reads) ----
#pragma unroll
        for (int kk = 0; kk < 4; ++kk) {
#pragma unroll
            for (int half = 0; half < 2; ++half) {
                int mt = kk * 2 + half;
                int c = half * 2 + (quad >> 1);
                int coff = ((c ^ cxor) * 8 + (quad & 1) * 4);
#pragma unroll
                for (int nt = 0; nt < 2; ++nt) {
                    us4 o;
#pragma unroll
                    for (int r = 0; r < 4; ++r) o[r] = f2bf(accs[mt][nt][r]);
                    *(us4*)&Pw[(nt * 16 + lc) * 40 + coff] = o;
                }
            }
            bf16x8 pf[2];
#pragma unroll
            for (int nt = 0; nt < 2; ++nt)
                pf[nt] = *(const bf16x8*)&Pw[(nt * 16 + lc) * 40 + (quad ^ cxor) * 8];
#pragma unroll
            for (int dt = 0; dt < 4; ++dt)
#pragma unroll
                for (int nt = 0; nt < 2; ++nt)
                    acco[dt][nt] = MFMA16(vf[kk][dt], pf[nt], acco[dt][nt]);
        }
        if (kt < 15) {
            // counted-vmcnt barrier: let the 8 NT bias stores float across; everything older
            // (glds16 K-prefetch, V loads) is in-order-retired at <=8 outstanding.
            asm volatile("s_waitcnt vmcnt(8) lgkmcnt(0)" ::: "memory");
            __builtin_amdgcn_s_barrier();
            __builtin_amdgcn_sched_barrier(0);
        }
    }

    // ---- epilogue: O^T lane holds (d = dt*16+quad*4+r, q = w*32+nt*16+lc) ----
#pragma unroll
    for (int nt = 0; nt < 2; ++nt) {
        float inv = 1.0f / lstate[nt];
        size_t row = tokbase + q0 + w * 32 + nt * 16 + lc;
#pragma unroll
        for (int dt = 0; dt < 4; ++dt) {
            us4 o;
#pragma unroll
            for (int r = 0; r < 4; ++r) o[r] = f2bf(acco[dt][nt][r] * inv);
            *(us4*)&Ctx[row * 1024 + h * 64 + dt * 16 + quad * 4] = o;
        }
    }
}

extern "C" void kernel_launch(void* const* d_in, const int* in_sizes, int n_in,
                              void* d_out, int out_size, void* d_ws, size_t ws_size,
                              hipStream_t stream) {
    const float* hidden = (const float*)d_in[0];
    const float* Wq = (const float*)d_in[1];
    const float* Wk = (const float*)d_in[2];
    const float* Wv = (const float*)d_in[3];
    const float* Wo = (const float*)d_in[4];
    const float* table = (const float*)d_in[5];

    char* ws = (char*)d_ws;
    ushort_t* Xb  = (ushort_t*)(ws);                    // [4096][1024] bf16
    ushort_t* Wb  = (ushort_t*)(ws + 8388608);          // Wq(*log2e),Wk,Wv,Wo each [1024][1024]
    ushort_t* Qg  = (ushort_t*)(ws + 16777216);         // [4096][1024]
    ushort_t* Kgp = (ushort_t*)(ws + 25165824);         // [4096][1024]
    ushort_t* VTg = (ushort_t*)(ws + 33554432);         // [(b*1024+f)][2048]
    ushort_t* Ctx = (ushort_t*)(ws + 41943040);         // [4096][1024]
    unsigned char* lutp = (unsigned char*)(ws + 50331648);

    float* out0 = (float*)d_out;
    float* out1 = out0 + 4194304;

    cast_all_k<<<2049, 256, 0, stream>>>(hidden, Wq, Wk, Wv, Wo, Xb, Wb, lutp);

    // Q, K projections + V^T in one fused dispatch (768 blocks = 3/CU perfect fit)
    gemm_qkvt_k<<<768, 256, 0, stream>>>(Xb, Wb, Qg, VTg);

    attn_k<<<dim3(512), 256, 0, stream>>>(Qg, Kgp, VTg, Ctx, lutp, table, out1);

    // output projection: 64x128 tiles -> 512 blocks (2/CU), XCD panel-grouped
    gemm_out_k<<<512, 256, 0, stream>>>(Ctx, Wb + 3145728, out0);
}